// Round 1
// baseline (584.053 us; speedup 1.0000x reference)
//
#include <hip/hip_runtime.h>
#include <stdint.h>

// Conv2d(64->128,3x3,VALID)+BN+scale, implicit-GEMM bf16 MFMA.
// v2: LDS-staged activations. Block = one output row (n,p): stages 3 contiguous
// xt rows (48 KB) once via global_load_lds(16B), single barrier, then the whole
// K-loop (18 chunks) reads B from LDS (XOR-swizzled, conflict-free) and A
// (weights, L2-resident) from global with register double-buffering.
// Swizzle is baked into xt by the pre-pass (linear LDS dest, pre-swizzled src).

typedef __attribute__((ext_vector_type(8))) short bf16x8;   // 8 bf16, 4 VGPRs
typedef __attribute__((ext_vector_type(4))) float f32x4;

#define C_IN   64
#define HW     128
#define K_OUT  128
#define QO     126
#define PQ     15876        // 126*126
#define KTOT   576          // 9*64, k = (r*3+s)*64 + c
#define ROWB   16384        // bytes per xt row: 128 px * 128 B
#define NBLK   4032         // 32 n * 126 p
#define CPX    504          // NBLK / 8 XCDs (exact)

__device__ __forceinline__ uint32_t f2bf(float f) {
    uint32_t u = __builtin_bit_cast(uint32_t, f);
    return (u + 0x7FFFu + ((u >> 16) & 1u)) >> 16;   // RNE
}
__device__ __forceinline__ uint32_t pack2(float a, float b) {
    return f2bf(a) | (f2bf(b) << 16);
}
__device__ __forceinline__ void gload_lds16(const void* g, void* l) {
    __builtin_amdgcn_global_load_lds(
        (const __attribute__((address_space(1))) void*)g,
        (__attribute__((address_space(3))) void*)l, 16, 0, 0);
}

// ---------- pre-pass 1: x NCHW f32 -> xt NHWC bf16, swizzle baked ----------
// Pixel (n,h,w): 128 B of 64 bf16 channels; dword cp stored at cp ^ ((w&7)<<2)
// (i.e. byte b stored at b ^ ((w&7)<<4); XOR touches 16B-slot bits only).
__global__ __launch_bounds__(256)
void xpose_kernel(const float* __restrict__ x, uint32_t* __restrict__ xt) {
    __shared__ float tile[HW][C_IN + 1];      // [w][c], pad -> conflict-free
    const int n   = blockIdx.x >> 7;
    const int h   = blockIdx.x & 127;
    const int tid = threadIdx.x;
    #pragma unroll
    for (int it = 0; it < 32; ++it) {
        int idx = it * 256 + tid;
        int c = idx >> 7, w = idx & 127;
        tile[w][c] = x[((n * C_IN + c) * HW + h) * HW + w];   // coalesced over w
    }
    __syncthreads();
    #pragma unroll
    for (int it = 0; it < 16; ++it) {
        int idx = it * 256 + tid;
        int w = idx >> 5, cp = idx & 31;
        xt[((n * HW + h) * HW + w) * 32 + (cp ^ ((w & 7) << 2))] =
            pack2(tile[w][cp * 2], tile[w][cp * 2 + 1]);      // still 128B-coalesced
    }
}

// ---------- pre-pass 2: W -> bf16 [o][tap][c]; alpha/beta ----------
__global__ __launch_bounds__(64)
void wprep_kernel(const float* __restrict__ W, const float* __restrict__ Bb,
                  const float* __restrict__ rmean, const float* __restrict__ rvar,
                  const float* __restrict__ bnw, const float* __restrict__ bnb,
                  const float* __restrict__ scl,
                  unsigned short* __restrict__ Wb,
                  float* __restrict__ alpha, float* __restrict__ beta) {
    const int o = blockIdx.x;       // out-channel
    const int c = threadIdx.x;      // in-channel
    #pragma unroll
    for (int t = 0; t < 9; ++t)
        Wb[(o * 9 + t) * 64 + c] = (unsigned short)f2bf(W[(o * 64 + c) * 9 + t]);
    if (c == 0) {
        float sc = scl[0];
        float a = rsqrtf(rvar[o] + 1e-5f) * bnw[o] * sc;
        alpha[o] = a;
        beta[o]  = (Bb[o] - rmean[o]) * a + bnb[o] * sc;
    }
}

// ---------- main: block = one output row (128 px x 128 ch), 4 waves 2x2 ----------
__global__ __launch_bounds__(256, 3)
void conv_main_kernel(const char* __restrict__ xt, const char* __restrict__ wb,
                      const float* __restrict__ alpha, const float* __restrict__ beta,
                      float* __restrict__ out) {
    __shared__ char ls[3 * ROWB] __attribute__((aligned(16)));   // 48 KB

    const int tid  = threadIdx.x;
    const int lane = tid & 63;
    const int wid  = tid >> 6;
    const int wm   = wid >> 1, wn = wid & 1;      // wm: ch-half, wn: px-half
    const int quad = lane >> 4, l16 = lane & 15;

    // XCD-bijective swizzle: consecutive work (same n, consecutive p) -> same XCD
    int wg = (blockIdx.x & 7) * CPX + (blockIdx.x >> 3);
    const int n = wg / QO;            // image 0..31
    const int p = wg - n * QO;        // output row 0..125

    // ---- stage 3 contiguous input rows p..p+2 into LDS (one linear 48 KB span)
    {
        const char* src = xt + (size_t)(n * HW + p) * ROWB;
        const int lbase = wid * 1024;
        const int gbase = wid * 1024 + (lane << 4);
        #pragma unroll
        for (int i = 0; i < 12; ++i)
            gload_lds16(src + i * 4096 + gbase, ls + i * 4096 + lbase);
    }

    // ---- A-fragment voffsets: Wb[m][k], lane m=l16, k=quad*8 (+cc*32 via imm)
    int vA[4];
    #pragma unroll
    for (int ms = 0; ms < 4; ++ms)
        vA[ms] = ((wm * 64 + ms * 16 + l16) * KTOT + quad * 8) * 2;

    // ---- B LDS base addrs per (ns, s): pixel w = q+s, bytes (quad*16)^((w&7)<<4)
    // parity (c0=32) adds ^64 (bit-disjoint with quad*16, commutes with the XOR).
    int lB[4][3];
    #pragma unroll
    for (int ns = 0; ns < 4; ++ns) {
        const int q = wn * 64 + ns * 16 + l16;
        #pragma unroll
        for (int s = 0; s < 3; ++s) {
            int w = q + s;
            w = w > 127 ? 127 : w;    // q>=126 lanes: clamped, results discarded
            lB[ns][s] = w * 128 + ((quad * 16) ^ ((w & 7) << 4));
        }
    }

    f32x4 acc[4][4];
    #pragma unroll
    for (int i = 0; i < 4; ++i)
        #pragma unroll
        for (int j = 0; j < 4; ++j)
            acc[i][j] = (f32x4){0.f, 0.f, 0.f, 0.f};

    // prefetch A chunk 0 (overlaps with staging; barrier drains both)
    bf16x8 Af[2][4];
    #pragma unroll
    for (int ms = 0; ms < 4; ++ms)
        Af[0][ms] = *(const bf16x8*)(wb + vA[ms]);

    __syncthreads();   // compiler emits vmcnt(0) here -> staging complete

    // ---- K-loop: 18 chunks of k=32; tap=cc>>1 (r,s), parity=cc&1 (c0=0/32).
    // B from LDS only (no barriers needed; LDS is read-only from here).
    #pragma unroll
    for (int cc = 0; cc < 18; ++cc) {
        const int cur = cc & 1, nxt = cur ^ 1;
        const int tap = cc >> 1;
        const int r   = tap / 3;
        const int s   = tap - r * 3;
        if (cc < 17) {
            #pragma unroll
            for (int ms = 0; ms < 4; ++ms)
                Af[nxt][ms] = *(const bf16x8*)(wb + vA[ms] + (cc + 1) * 64);
        }
        bf16x8 Bf[4];
        #pragma unroll
        for (int ns = 0; ns < 4; ++ns) {
            const int lb = lB[ns][s] ^ (cur ? 64 : 0);
            Bf[ns] = *(const bf16x8*)(ls + lb + r * ROWB);
        }
        #pragma unroll
        for (int ms = 0; ms < 4; ++ms)
            #pragma unroll
            for (int ns = 0; ns < 4; ++ns)
                acc[ms][ns] = __builtin_amdgcn_mfma_f32_16x16x32_bf16(
                    Af[cur][ms], Bf[ns], acc[ms][ns], 0, 0, 0);
    }

    // ---- epilogue: out[n][k][p][q] = acc*alpha[k] + beta[k]
    // C/D layout: col(pixel)=lane&15, row(channel)=quad*4+reg
    #pragma unroll
    for (int ns = 0; ns < 4; ++ns) {
        const int q = wn * 64 + ns * 16 + l16;
        if (q < QO) {
            #pragma unroll
            for (int ms = 0; ms < 4; ++ms) {
                const int kb = wm * 64 + ms * 16 + quad * 4;
                const f32x4 al = *(const f32x4*)(alpha + kb);
                const f32x4 be = *(const f32x4*)(beta + kb);
                #pragma unroll
                for (int rr = 0; rr < 4; ++rr)
                    out[((n * K_OUT + kb + rr) * QO + p) * QO + q] =
                        acc[ms][ns][rr] * al[rr] + be[rr];
            }
        }
    }
}

extern "C" void kernel_launch(void* const* d_in, const int* in_sizes, int n_in,
                              void* d_out, int out_size, void* d_ws, size_t ws_size,
                              hipStream_t stream) {
    const float* x     = (const float*)d_in[0];
    const float* Wt    = (const float*)d_in[1];
    const float* Bb    = (const float*)d_in[2];
    const float* rmean = (const float*)d_in[3];
    const float* rvar  = (const float*)d_in[4];
    const float* bnw   = (const float*)d_in[5];
    const float* bnb   = (const float*)d_in[6];
    const float* scl   = (const float*)d_in[7];
    float* out = (float*)d_out;

    char* ws = (char*)d_ws;
    uint32_t*       xt    = (uint32_t*)ws;                       // 64 MiB NHWC bf16 (swizzled)
    unsigned short* Wb    = (unsigned short*)(ws + 67108864);    // 147456 B
    float*          alpha = (float*)(ws + 67108864 + 147456);    // 512 B
    float*          beta  = alpha + 128;                         // 512 B

    xpose_kernel<<<32 * 128, 256, 0, stream>>>(x, xt);
    wprep_kernel<<<128, 64, 0, stream>>>(Wt, Bb, rmean, rvar, bnw, bnb, scl,
                                         Wb, alpha, beta);
    conv_main_kernel<<<NBLK, 256, 0, stream>>>((const char*)xt, (const char*)Wb,
                                               alpha, beta, out);
}

// Round 2
// 570.874 us; speedup vs baseline: 1.0231x; 1.0231x over previous
//
#include <hip/hip_runtime.h>
#include <stdint.h>

// Conv2d(64->128,3x3,VALID)+BN+scale, implicit-GEMM bf16 MFMA.
// v3: p-strip rolling LDS buffer. Block = (n, 9 output rows). 4-slot (64 KB)
// circular row buffer: stage ONE 16 KB xt row per iteration (overlapped with
// the 18-chunk MFMA loop), barrier once per iteration. Staging per output row
// drops 48->19.5 KB; consecutive p-rows written by the same block (write-merge).
// xt is pre-swizzled (XOR in 16B slots) so LDS ds_read_b128 is conflict-free
// while global_load_lds destinations stay linear.

typedef __attribute__((ext_vector_type(8))) short bf16x8;   // 8 bf16, 4 VGPRs
typedef __attribute__((ext_vector_type(4))) float f32x4;

#define C_IN   64
#define HW     128
#define K_OUT  128
#define QO     126
#define PQ     15876        // 126*126
#define KTOT   576          // 9*64, k = (r*3+s)*64 + c
#define ROWB   16384        // bytes per xt row: 128 px * 128 B
#define PS     9            // output rows per block strip
#define NSTRIP 14           // 126 / 9
#define NBLK   448          // 32 n * 14 strips  (= 8 XCD * 56)
#define CPX    56

__device__ __forceinline__ uint32_t f2bf(float f) {
    uint32_t u = __builtin_bit_cast(uint32_t, f);
    return (u + 0x7FFFu + ((u >> 16) & 1u)) >> 16;   // RNE
}
__device__ __forceinline__ uint32_t pack2(float a, float b) {
    return f2bf(a) | (f2bf(b) << 16);
}
__device__ __forceinline__ void gload_lds16(const void* g, void* l) {
    __builtin_amdgcn_global_load_lds(
        (const __attribute__((address_space(1))) void*)g,
        (__attribute__((address_space(3))) void*)l, 16, 0, 0);
}
// stage one 16 KB xt row: 4 passes of 256 threads x 16 B (dst linear, lane-ordered)
__device__ __forceinline__ void stage_row(const char* src_row, char* lds_row) {
    #pragma unroll
    for (int i = 0; i < 4; ++i)
        gload_lds16(src_row + i * 4096, lds_row + i * 4096);
}

// ---------- pre-pass 1: x NCHW f32 -> xt NHWC bf16, swizzle baked ----------
// Pixel (n,h,w): 128 B of 64 bf16 channels; dword cp stored at cp ^ ((w&7)<<2)
// (i.e. byte b stored at b ^ ((w&7)<<4); XOR touches 16B-slot bits only).
__global__ __launch_bounds__(256)
void xpose_kernel(const float* __restrict__ x, uint32_t* __restrict__ xt) {
    __shared__ float tile[HW][C_IN + 1];      // [w][c], pad -> conflict-free
    const int n   = blockIdx.x >> 7;
    const int h   = blockIdx.x & 127;
    const int tid = threadIdx.x;
    #pragma unroll
    for (int it = 0; it < 32; ++it) {
        int idx = it * 256 + tid;
        int c = idx >> 7, w = idx & 127;
        tile[w][c] = x[((n * C_IN + c) * HW + h) * HW + w];   // coalesced over w
    }
    __syncthreads();
    #pragma unroll
    for (int it = 0; it < 16; ++it) {
        int idx = it * 256 + tid;
        int w = idx >> 5, cp = idx & 31;
        xt[((n * HW + h) * HW + w) * 32 + (cp ^ ((w & 7) << 2))] =
            pack2(tile[w][cp * 2], tile[w][cp * 2 + 1]);      // still 128B-coalesced
    }
}

// ---------- pre-pass 2: W -> bf16 [o][tap][c]; alpha/beta ----------
__global__ __launch_bounds__(64)
void wprep_kernel(const float* __restrict__ W, const float* __restrict__ Bb,
                  const float* __restrict__ rmean, const float* __restrict__ rvar,
                  const float* __restrict__ bnw, const float* __restrict__ bnb,
                  const float* __restrict__ scl,
                  unsigned short* __restrict__ Wb,
                  float* __restrict__ alpha, float* __restrict__ beta) {
    const int o = blockIdx.x;       // out-channel
    const int c = threadIdx.x;      // in-channel
    #pragma unroll
    for (int t = 0; t < 9; ++t)
        Wb[(o * 9 + t) * 64 + c] = (unsigned short)f2bf(W[(o * 64 + c) * 9 + t]);
    if (c == 0) {
        float sc = scl[0];
        float a = rsqrtf(rvar[o] + 1e-5f) * bnw[o] * sc;
        alpha[o] = a;
        beta[o]  = (Bb[o] - rmean[o]) * a + bnb[o] * sc;
    }
}

// ---------- main: block = (n, 9-row strip), 4 waves 2x2, rolling 4-slot LDS ----------
__global__ __launch_bounds__(256, 2)
void conv_main_kernel(const char* __restrict__ xt, const char* __restrict__ wb,
                      const float* __restrict__ alpha, const float* __restrict__ beta,
                      float* __restrict__ out) {
    __shared__ char ls[4 * ROWB] __attribute__((aligned(16)));   // 64 KB

    const int tid  = threadIdx.x;
    const int lane = tid & 63;
    const int wid  = tid >> 6;
    const int wm   = wid >> 1, wn = wid & 1;      // wm: ch-half, wn: px-half
    const int quad = lane >> 4, l16 = lane & 15;

    // XCD-bijective swizzle: consecutive wg (same n, consecutive strips) -> same XCD
    const int wg = (blockIdx.x & 7) * CPX + (blockIdx.x >> 3);
    const int n  = wg / NSTRIP;
    const int p0 = (wg - n * NSTRIP) * PS;

    const char* src  = xt + (size_t)(n * HW + p0) * ROWB;   // rel rows 0..PS+1
    const int   toff = tid << 4;

    // prologue: stage rel rows 0,1,2 -> slots 0,1,2
    stage_row(src + 0 * ROWB + toff, ls + 0 * ROWB + toff);
    stage_row(src + 1 * ROWB + toff, ls + 1 * ROWB + toff);
    stage_row(src + 2 * ROWB + toff, ls + 2 * ROWB + toff);

    // A-fragment voffsets: Wb[m][k], lane m=l16, k=quad*8 (+cc*32 via imm)
    int vA[4];
    #pragma unroll
    for (int ms = 0; ms < 4; ++ms)
        vA[ms] = ((wm * 64 + ms * 16 + l16) * KTOT + quad * 8) * 2;

    // B in-row LDS offsets per (ns, s): pixel w=q+s, bytes (quad*16)^((w&7)<<4);
    // parity (c0=32) toggles bit6, which commutes with the XOR.
    int lB[4][3];
    #pragma unroll
    for (int ns = 0; ns < 4; ++ns) {
        const int q = wn * 64 + ns * 16 + l16;
        #pragma unroll
        for (int s = 0; s < 3; ++s) {
            int w = q + s;
            w = w > 127 ? 127 : w;    // q>=126 lanes: clamped, results discarded
            lB[ns][s] = w * 128 + ((quad * 16) ^ ((w & 7) << 4));
        }
    }

    f32x4 acc[4][4];
    #pragma unroll
    for (int i = 0; i < 4; ++i)
        #pragma unroll
        for (int j = 0; j < 4; ++j)
            acc[i][j] = (f32x4){0.f, 0.f, 0.f, 0.f};

    __syncthreads();   // drain prologue staging (vmcnt(0) implied)

    #pragma unroll 1
    for (int i = 0; i < PS; ++i) {
        // issue next row's staging early; it has the whole MFMA loop to land.
        // slot (i+3)&3 was last read in iter i-1 -> protected by iter i-1 barrier.
        if (i < PS - 1)
            stage_row(src + (i + 3) * ROWB + toff,
                      ls + ((i + 3) & 3) * ROWB + toff);

        const int sbase[3] = { (i & 3) * ROWB, ((i + 1) & 3) * ROWB,
                               ((i + 2) & 3) * ROWB };

        bf16x8 Af[2][4];
        #pragma unroll
        for (int ms = 0; ms < 4; ++ms)
            Af[0][ms] = *(const bf16x8*)(wb + vA[ms]);     // chunk 0 (L1-hot)

        #pragma unroll
        for (int cc = 0; cc < 18; ++cc) {
            const int cur = cc & 1, nxt = cur ^ 1;
            const int tap = cc >> 1;
            const int r   = tap / 3;
            const int s   = tap - r * 3;
            if (cc < 17) {
                #pragma unroll
                for (int ms = 0; ms < 4; ++ms)
                    Af[nxt][ms] = *(const bf16x8*)(wb + vA[ms] + (cc + 1) * 64);
            }
            bf16x8 Bf[4];
            #pragma unroll
            for (int ns = 0; ns < 4; ++ns)
                Bf[ns] = *(const bf16x8*)(ls + sbase[r] +
                                          (lB[ns][s] ^ (cur ? 64 : 0)));
            #pragma unroll
            for (int ms = 0; ms < 4; ++ms)
                #pragma unroll
                for (int ns = 0; ns < 4; ++ns)
                    acc[ms][ns] = __builtin_amdgcn_mfma_f32_16x16x32_bf16(
                        Af[cur][ms], Bf[ns], acc[ms][ns], 0, 0, 0);
        }

        __syncthreads();   // all waves done reading slots i..i+2; stage landed

        // epilogue (after barrier: stores drain at NEXT iteration's barrier)
        // C/D layout: col(pixel)=lane&15, row(channel)=quad*4+reg
        const int p = p0 + i;
        #pragma unroll
        for (int ns = 0; ns < 4; ++ns) {
            const int q = wn * 64 + ns * 16 + l16;
            if (q < QO) {
                #pragma unroll
                for (int ms = 0; ms < 4; ++ms) {
                    const int kb = wm * 64 + ms * 16 + quad * 4;
                    const f32x4 al = *(const f32x4*)(alpha + kb);
                    const f32x4 be = *(const f32x4*)(beta + kb);
                    #pragma unroll
                    for (int rr = 0; rr < 4; ++rr)
                        out[((n * K_OUT + kb + rr) * QO + p) * QO + q] =
                            acc[ms][ns][rr] * al[rr] + be[rr];
                }
            }
        }
        #pragma unroll
        for (int a = 0; a < 4; ++a)
            #pragma unroll
            for (int b = 0; b < 4; ++b)
                acc[a][b] = (f32x4){0.f, 0.f, 0.f, 0.f};
    }
}

extern "C" void kernel_launch(void* const* d_in, const int* in_sizes, int n_in,
                              void* d_out, int out_size, void* d_ws, size_t ws_size,
                              hipStream_t stream) {
    const float* x     = (const float*)d_in[0];
    const float* Wt    = (const float*)d_in[1];
    const float* Bb    = (const float*)d_in[2];
    const float* rmean = (const float*)d_in[3];
    const float* rvar  = (const float*)d_in[4];
    const float* bnw   = (const float*)d_in[5];
    const float* bnb   = (const float*)d_in[6];
    const float* scl   = (const float*)d_in[7];
    float* out = (float*)d_out;

    char* ws = (char*)d_ws;
    uint32_t*       xt    = (uint32_t*)ws;                       // 64 MiB NHWC bf16 (swizzled)
    unsigned short* Wb    = (unsigned short*)(ws + 67108864);    // 147456 B
    float*          alpha = (float*)(ws + 67108864 + 147456);    // 512 B
    float*          beta  = alpha + 128;                         // 512 B

    xpose_kernel<<<32 * 128, 256, 0, stream>>>(x, xt);
    wprep_kernel<<<128, 64, 0, stream>>>(Wt, Bb, rmean, rvar, bnw, bnb, scl,
                                         Wb, alpha, beta);
    conv_main_kernel<<<NBLK, 256, 0, stream>>>((const char*)xt, (const char*)Wb,
                                               alpha, beta, out);
}